// Round 16
// baseline (326.506 us; speedup 1.0000x reference)
//
#include <hip/hip_runtime.h>
#include <hip/hip_bf16.h>

constexpr int TSEQ  = 2048;
constexpr int HDIM  = 1024;
constexpr int BATCH = 32;
constexpr int NPART = 16;
constexpr long ROWS = (long)BATCH * TSEQ;  // 65536

// GEMM geometry: 256(M) x 128(N) block, 8 waves (4M x 2N), 64x64 wave tile
constexpr int GBM = 256, GBN = 128;

// fallback (R1) geometry
constexpr int BM = 128, BN = 128, BK = 64;
constexpr int NT = (2 * HDIM) / BK;

typedef __attribute__((ext_vector_type(8))) short bf16x8;
typedef __attribute__((ext_vector_type(8))) unsigned short u16x8;
typedef __attribute__((ext_vector_type(4))) float f32x4;

__device__ __forceinline__ unsigned short f2bf(float f) {
    union { float f; unsigned int u; } v; v.f = f;
    unsigned int r = v.u + 0x7FFFu + ((v.u >> 16) & 1u);  // RTNE
    return (unsigned short)(r >> 16);
}

__device__ __forceinline__ void gload16(const unsigned short* g, unsigned short* l) {
    __builtin_amdgcn_global_load_lds(
        (__attribute__((address_space(1))) void*)(g),
        (__attribute__((address_space(3))) void*)(l), 16, 0, 0);
}

__device__ __forceinline__ float fast_tanh(float x) {
    float e = __expf(2.0f * x);
    return 1.0f - 2.0f * __builtin_amdgcn_rcpf(e + 1.0f);
}

// ---------------- f32 -> bf16 pre-convert (skips masked q/k rows) ----------------
__global__ void convert_kernel(const float* __restrict__ q, const float* __restrict__ k,
                               const float* __restrict__ wq, const float* __restrict__ wk,
                               const int* __restrict__ lengths,
                               unsigned short* __restrict__ qb, unsigned short* __restrict__ kb,
                               unsigned short* __restrict__ wqb, unsigned short* __restrict__ wkb) {
    const long GQ = (ROWS * HDIM) / 8;        // groups of 8 elems
    const long GW = ((long)HDIM * HDIM) / 8;
    const long TOTAL = 2 * GQ + 2 * GW;
    const long stride = (long)gridDim.x * blockDim.x;
    for (long i = (long)blockIdx.x * blockDim.x + threadIdx.x; i < TOTAL; i += stride) {
        const float* src; unsigned short* dst; long off;
        if (i < 2 * GQ) {
            off = (i < GQ) ? i : i - GQ;
            const int row = (int)(off >> 7);                    // HDIM/8 = 128 groups/row
            if ((row & (TSEQ - 1)) >= lengths[row >> 11]) continue;  // masked row: skip
            src = (i < GQ) ? q : k;  dst = (i < GQ) ? qb : kb;
        } else if (i < 2 * GQ + GW) { src = wq; dst = wqb; off = i - 2 * GQ; }
        else                        { src = wk; dst = wkb; off = i - 2 * GQ - GW; }
        float4 v0 = *(const float4*)(src + off * 8);
        float4 v1 = *(const float4*)(src + off * 8 + 4);
        u16x8 o;
        o[0] = f2bf(v0.x); o[1] = f2bf(v0.y); o[2] = f2bf(v0.z); o[3] = f2bf(v0.w);
        o[4] = f2bf(v1.x); o[5] = f2bf(v1.y); o[6] = f2bf(v1.z); o[7] = f2bf(v1.w);
        *(u16x8*)(dst + off * 8) = o;
    }
}

// ------- 256x128 bf16 GEMM: 64x64 wave tile, ring-3 LDS (72 KiB), 2 blocks/CU. -------
// R13 schedule with: NO setprio (m190: setprio harms non-8-phase GEMM by starving the
// co-resident block's staging waves) and x3-peeled static ring slots. Phase n: 8 ds_read
// slot n%3; stage(n+2) -> slot (n+2)%3 (3 gloads); lgkm(0); 16 MFMA; vmcnt(3); barrier.
__global__ __launch_bounds__(512, 4)
void score_gemm_256(const unsigned short* __restrict__ qb, const unsigned short* __restrict__ kb,
                    const unsigned short* __restrict__ wqb, const unsigned short* __restrict__ wkb,
                    const float* __restrict__ bq, const float* __restrict__ bk,
                    const float* __restrict__ Wz, const int* __restrict__ lengths,
                    float* __restrict__ scorePartial) {
    __shared__ unsigned short As[3 * 256 * 32];  // 48 KiB: ring-3 of A k-halves
    __shared__ unsigned short Bs[3 * 128 * 32];  // 24 KiB: ring-3 of B k-halves

    const int tid  = threadIdx.x;
    const int lane = tid & 63;
    const int wid  = tid >> 6;    // 0..7
    const int wr   = wid >> 1;    // WARPS_M = 4
    const int wc   = wid & 1;     // WARPS_N = 2

    // locality-preserving balanced remap (validated R13): XCD x gets one intra-batch
    // M-slot per batch (rotated); all 8 nb-siblings of an A-panel dispatch-adjacent.
    const int x   = (int)blockIdx.x & 7;
    const int j   = (int)blockIdx.x >> 3;      // 0..255
    const int bat = j >> 3;                    // batch 0..31
    const int nb  = j & 7;                     // 8 N-blocks
    const int mb  = bat * 8 + ((x + bat) & 7); // rotated intra-batch M index
    const long rowBase = (long)mb * GBM;
    const int  colBase = nb * GBN;

    if (((mb & 7) * GBM) >= lengths[bat]) return;   // fully-masked M-block

    const int frow = lane & 15;
    const int cs16 = (((lane >> 4) ^ ((frow >> 1) & 3)) << 4);   // read chunk (XOR-swz)
    const int sc8  = ((tid & 3) ^ ((tid >> 3) & 3)) * 8;         // pre-swizzled source chunk
    const int rowA = wr * 64 + frow;
    const int rowB = wc * 64 + frow;

    f32x4 acc[4][4];
#pragma unroll
    for (int i = 0; i < 4; ++i)
#pragma unroll
        for (int j2 = 0; j2 < 4; ++j2) acc[i][j2] = (f32x4){0.f, 0.f, 0.f, 0.f};

    // stage k-half n into ring slot s: A 16KB (2 rounds) + B 8KB (1 round)
    auto stage = [&](int n, int s) {
        const int tn = n >> 1;
        const unsigned short* asrc = (tn < 16) ? qb : kb;
        const unsigned short* bsrc = (tn < 16) ? wqb : wkb;
        const int ksrc = (tn & 15) * 64 + (n & 1) * 32 + sc8;
        unsigned short* ldsA = As + s * 8192;
        unsigned short* ldsB = Bs + s * 4096;
#pragma unroll
        for (int jj = 0; jj < 2; ++jj)
            gload16(asrc + (rowBase + jj * 128 + (tid >> 2)) * (long)HDIM + ksrc,
                    ldsA + jj * 4096 + (tid << 3));
        gload16(bsrc + (long)(colBase + (tid >> 2)) * HDIM + ksrc, ldsB + (tid << 3));
    };

    // prologue: stage halves 0,1; drain half 0 (vmcnt(3) keeps stage(1) in flight)
    stage(0, 0);
    stage(1, 1);
    asm volatile("s_waitcnt vmcnt(3)" ::: "memory");
    __builtin_amdgcn_s_barrier();

#define BODY(N, CUR, TGT, DO_STAGE, VMC)                                         \
    {                                                                            \
        const char* pA = (const char*)As + (CUR) * 16384;                        \
        const char* pB = (const char*)Bs + (CUR) * 8192;                         \
        bf16x8 afr[4], bfr[4];                                                   \
        _Pragma("unroll") for (int mi = 0; mi < 4; ++mi)                         \
            afr[mi] = *(const bf16x8*)(pA + (rowA + mi * 16) * 64 + cs16);       \
        _Pragma("unroll") for (int ni = 0; ni < 4; ++ni)                         \
            bfr[ni] = *(const bf16x8*)(pB + (rowB + ni * 16) * 64 + cs16);       \
        if (DO_STAGE) stage((N) + 2, TGT);                                       \
        asm volatile("s_waitcnt lgkmcnt(0)" ::: "memory");                       \
        __builtin_amdgcn_sched_barrier(0);                                       \
        _Pragma("unroll") for (int mi = 0; mi < 4; ++mi)                         \
            _Pragma("unroll") for (int ni = 0; ni < 4; ++ni)                     \
                acc[mi][ni] = __builtin_amdgcn_mfma_f32_16x16x32_bf16(           \
                    afr[mi], bfr[ni], acc[mi][ni], 0, 0, 0);                     \
        if ((VMC) == 3)      asm volatile("s_waitcnt vmcnt(3)" ::: "memory");    \
        else if ((VMC) == 0) asm volatile("s_waitcnt vmcnt(0)" ::: "memory");    \
        if ((VMC) >= 0) __builtin_amdgcn_s_barrier();                            \
    }

    for (int i = 0; i < 20; ++i) {        // phases 0..59, static ring slots
        const int n = i * 3;
        BODY(n + 0, 0, 2, 1, 3);
        BODY(n + 1, 1, 0, 1, 3);
        BODY(n + 2, 2, 1, 1, 3);
    }
    BODY(60, 0, 2, 1, 3);                 // stage 62 -> slot 2
    BODY(61, 1, 0, 1, 3);                 // stage 63 -> slot 0
    BODY(62, 2, 1, 0, 0);                 // no stage; drain all
    BODY(63, 0, 0, 0, -1);                // last compute, no trailing sync
#undef BODY

    // epilogue: p[row] = sum_cols tanh(s + bq + bk) * Wz
    float bias[4], wz[4];
#pragma unroll
    for (int ni = 0; ni < 4; ++ni) {
        const int o = colBase + wc * 64 + ni * 16 + frow;
        bias[ni] = bq[o] + bk[o];
        wz[ni]   = Wz[o];
    }
#pragma unroll
    for (int mi = 0; mi < 4; ++mi) {
#pragma unroll
        for (int jj = 0; jj < 4; ++jj) {
            float p = 0.f;
#pragma unroll
            for (int ni = 0; ni < 4; ++ni)
                p += fast_tanh(acc[mi][ni][jj] + bias[ni]) * wz[ni];
#pragma unroll
            for (int off = 1; off < 16; off <<= 1) p += __shfl_xor(p, off);
            if (frow == 0) {
                long r = rowBase + wr * 64 + mi * 16 + (lane >> 4) * 4 + jj;
                scorePartial[r * NPART + nb * 2 + wc] = p;
            }
        }
    }
}

// ---------------- fallback: round-1 fused f32 GEMM (with early-out) ----------------
__global__ __launch_bounds__(256, 2)
void score_gemm_fused(const float* __restrict__ query, const float* __restrict__ key_,
                      const float* __restrict__ Wq, const float* __restrict__ Wk,
                      const float* __restrict__ bq, const float* __restrict__ bk,
                      const float* __restrict__ Wz, const int* __restrict__ lengths,
                      float* __restrict__ scorePartial) {
    __shared__ unsigned short As[2][BM * BK];
    __shared__ unsigned short Bs[2][BN * BK];
    const int tid  = threadIdx.x;
    const int lane = tid & 63;
    const int wid  = tid >> 6;
    const int wr   = wid >> 1, wc = wid & 1;
    const int bid = blockIdx.x;
    const int nb  = bid & 7;
    const int mb  = bid >> 3;
    const long rowBase = (long)mb * BM;
    const int  colBase = nb * BN;
    if ((int)(rowBase & (TSEQ - 1)) >= lengths[(int)(rowBase >> 11)]) return;
    const int srow = tid >> 4;
    const int sc   = tid & 15;
    const int rA  = wr * 64 + (lane & 15);
    const int rB  = wc * 64 + (lane & 15);
    const int swz = (lane & 7) << 4;
    const int kb  = (lane >> 4) << 4;

    f32x4 acc[4][4];
#pragma unroll
    for (int i = 0; i < 4; i++)
#pragma unroll
        for (int j = 0; j < 4; j++) acc[i][j] = (f32x4){0.f, 0.f, 0.f, 0.f};

    float4 regA[8], regB[8];
    auto stage_load = [&](int kt) {
        const int kg = kt * BK;
        const float* baseA; const float* baseB; int koff;
        if (kg < HDIM) { baseA = query; baseB = Wq; koff = kg; }
        else           { baseA = key_;  baseB = Wk; koff = kg - HDIM; }
#pragma unroll
        for (int i = 0; i < 8; i++) {
            int row = i * 16 + srow;
            regA[i] = *(const float4*)(baseA + (rowBase + row) * (long)HDIM + koff + sc * 4);
            regB[i] = *(const float4*)(baseB + (long)(colBase + row) * HDIM + koff + sc * 4);
        }
    };
    auto stage_write = [&](int buf) {
#pragma unroll
        for (int i = 0; i < 8; i++) {
            int row = i * 16 + srow;
            int off = row * 128 + (((sc * 8)) ^ ((row & 7) << 4));
            ushort4 ha, hb;
            ha.x = f2bf(regA[i].x); ha.y = f2bf(regA[i].y);
            ha.z = f2bf(regA[i].z); ha.w = f2bf(regA[i].w);
            hb.x = f2bf(regB[i].x); hb.y = f2bf(regB[i].y);
            hb.z = f2bf(regB[i].z); hb.w = f2bf(regB[i].w);
            *(ushort4*)((char*)&As[buf][0] + off) = ha;
            *(ushort4*)((char*)&Bs[buf][0] + off) = hb;
        }
    };
    auto compute = [&](int buf) {
        const char* pA = (const char*)&As[buf][0];
        const char* pB = (const char*)&Bs[buf][0];
        bf16x8 a[4][2], b[4][2];
#pragma unroll
        for (int h = 0; h < 2; h++) {
#pragma unroll
            for (int mi = 0; mi < 4; mi++)
                a[mi][h] = *(const bf16x8*)(pA + (((rA + mi * 16) * 128 + h * 64 + kb) ^ swz));
#pragma unroll
            for (int ni = 0; ni < 4; ni++)
                b[ni][h] = *(const bf16x8*)(pB + (((rB + ni * 16) * 128 + h * 64 + kb) ^ swz));
        }
#pragma unroll
        for (int h = 0; h < 2; h++)
#pragma unroll
            for (int mi = 0; mi < 4; mi++)
#pragma unroll
                for (int ni = 0; ni < 4; ni++)
                    acc[mi][ni] = __builtin_amdgcn_mfma_f32_16x16x32_bf16(
                        a[mi][h], b[ni][h], acc[mi][ni], 0, 0, 0);
    };

    stage_load(0);
    stage_write(0);
    __syncthreads();
    int buf = 0;
    for (int kt = 1; kt < NT; ++kt) {
        stage_load(kt);
        compute(buf);
        stage_write(buf ^ 1);
        __syncthreads();
        buf ^= 1;
    }
    compute(buf);

    float bias[4], wz[4];
#pragma unroll
    for (int ni = 0; ni < 4; ni++) {
        int o = colBase + wc * 64 + ni * 16 + (lane & 15);
        bias[ni] = bq[o] + bk[o];
        wz[ni]   = Wz[o];
    }
#pragma unroll
    for (int mi = 0; mi < 4; mi++) {
#pragma unroll
        for (int j = 0; j < 4; j++) {
            float p = 0.f;
#pragma unroll
            for (int ni = 0; ni < 4; ni++) {
                float s = acc[mi][ni][j] + bias[ni];
                p += fast_tanh(s) * wz[ni];
            }
#pragma unroll
            for (int off = 1; off < 16; off <<= 1) p += __shfl_xor(p, off);
            if ((lane & 15) == 0) {
                long r = rowBase + wr * 64 + mi * 16 + (lane >> 4) * 4 + j;
                scorePartial[r * NPART + nb * 2 + wc] = p;
            }
        }
    }
}

// ---------------- shared tail kernels ----------------
__global__ void softmax_kernel(const float* __restrict__ sp, const float* __restrict__ bzp,
                               const int* __restrict__ lengths,
                               float* __restrict__ w_out, float* __restrict__ w_ws) {
    const int b = blockIdx.x;
    const int tid = threadIdx.x;  // 256
    const int len = lengths[b];
    const float bz = bzp[0];
    float sv[8];
    float m = -3.0e38f;
#pragma unroll
    for (int i = 0; i < 8; i++) {
        int t = i * 256 + tid;
        const float4* p = (const float4*)(sp + ((long)b * TSEQ + t) * NPART);
        float s;
        if (t >= len) {
            s = -1e9f;   // masked: never read sp (may be unwritten garbage)
        } else {
            float4 a = p[0], c = p[1], d = p[2], e = p[3];
            s = (a.x + a.y + a.z + a.w) + (c.x + c.y + c.z + c.w) +
                (d.x + d.y + d.z + d.w) + (e.x + e.y + e.z + e.w) + bz;
        }
        sv[i] = s;
        m = fmaxf(m, s);
    }
    __shared__ float redm[4];
    __shared__ float reds[4];
    for (int off = 32; off; off >>= 1) m = fmaxf(m, __shfl_xor(m, off));
    if ((tid & 63) == 0) redm[tid >> 6] = m;
    __syncthreads();
    m = fmaxf(fmaxf(redm[0], redm[1]), fmaxf(redm[2], redm[3]));
    float sum = 0.f;
    float ev[8];
#pragma unroll
    for (int i = 0; i < 8; i++) {
        ev[i] = expf(sv[i] - m);
        sum += ev[i];
    }
    for (int off = 32; off; off >>= 1) sum += __shfl_xor(sum, off);
    if ((tid & 63) == 0) reds[tid >> 6] = sum;
    __syncthreads();
    sum = reds[0] + reds[1] + reds[2] + reds[3];
    const float inv = 1.0f / sum;
#pragma unroll
    for (int i = 0; i < 8; i++) {
        int t = i * 256 + tid;
        float w = ev[i] * inv;
        w_out[(long)b * TSEQ + t] = w;
        w_ws[(long)b * TSEQ + t] = w;
    }
}

__global__ void pv_partial(const float* __restrict__ w, const float* __restrict__ value,
                           const int* __restrict__ lengths, float* __restrict__ part) {
    const int ntc = gridDim.x;
    const int tchunk = TSEQ / ntc;
    const int tc = blockIdx.x;
    const int hc = blockIdx.y;
    const int b  = blockIdx.z;
    const int tid = threadIdx.x; // 128
    const int h = hc * 512 + tid * 4;
    float* dst = part + ((long)(b * ntc + tc)) * HDIM + h;
    if (tc * tchunk >= lengths[b]) {    // fully-masked chunk: zero partial, skip loads
        *(float4*)dst = (float4){0.f, 0.f, 0.f, 0.f};
        return;
    }
    __shared__ float sw[128];
    if (tid < tchunk) sw[tid] = w[(long)b * TSEQ + tc * tchunk + tid];
    __syncthreads();
    float4 acc = {0.f, 0.f, 0.f, 0.f};
    const float* vbase = value + ((long)b * TSEQ + tc * tchunk) * HDIM + h;
#pragma unroll 4
    for (int tt = 0; tt < tchunk; ++tt) {
        float4 v = *(const float4*)(vbase + (long)tt * HDIM);
        float wv = sw[tt];
        acc.x += wv * v.x; acc.y += wv * v.y;
        acc.z += wv * v.z; acc.w += wv * v.w;
    }
    *(float4*)dst = acc;
}

__global__ void pv_reduce(const float* __restrict__ part, float* __restrict__ out, int ntc) {
    const int b = blockIdx.x;    // 32
    const int tid = threadIdx.x; // 256
    const int h = tid * 4;
    float4 acc = {0.f, 0.f, 0.f, 0.f};
    for (int tc = 0; tc < ntc; ++tc) {
        float4 v = *(const float4*)(part + ((long)(b * ntc + tc)) * HDIM + h);
        acc.x += v.x; acc.y += v.y; acc.z += v.z; acc.w += v.w;
    }
    *(float4*)(out + (long)b * HDIM + h) = acc;
}

extern "C" void kernel_launch(void* const* d_in, const int* in_sizes, int n_in,
                              void* d_out, int out_size, void* d_ws, size_t ws_size,
                              hipStream_t stream) {
    const float* query   = (const float*)d_in[0];
    const float* key_    = (const float*)d_in[1];
    const float* value   = (const float*)d_in[2];
    const int*   lengths = (const int*)d_in[3];
    const float* Wq = (const float*)d_in[4];
    const float* bq = (const float*)d_in[5];
    const float* Wk = (const float*)d_in[6];
    const float* bk = (const float*)d_in[7];
    const float* Wz = (const float*)d_in[8];
    const float* bz = (const float*)d_in[9];
    float* out = (float*)d_out;

    const long QB_B  = ROWS * HDIM * 2;
    const long WB_B  = (long)HDIM * HDIM * 2;
    const long SP_B  = ROWS * NPART * 4;
    const long WW_B  = ROWS * 4;
    const long P2_B  = (long)BATCH * 32 * HDIM * 4;
    const long NEED  = 2 * QB_B + 2 * WB_B + SP_B + WW_B + P2_B;

    if ((long)ws_size >= NEED) {
        char* w = (char*)d_ws;
        unsigned short* qb  = (unsigned short*)w;            w += QB_B;
        unsigned short* kb  = (unsigned short*)w;            w += QB_B;
        unsigned short* wqb = (unsigned short*)w;            w += WB_B;
        unsigned short* wkb = (unsigned short*)w;            w += WB_B;
        float* sp   = (float*)w;                             w += SP_B;
        float* wbuf = (float*)w;                             w += WW_B;
        float* p2   = (float*)w;

        convert_kernel<<<dim3(4096), dim3(256), 0, stream>>>(
            query, key_, Wq, Wk, lengths, qb, kb, wqb, wkb);
        // grid = 256 M-blocks x 8 N-blocks = 2048
        score_gemm_256<<<dim3(2048), dim3(512), 0, stream>>>(
            qb, kb, wqb, wkb, bq, bk, Wz, lengths, sp);
        softmax_kernel<<<dim3(BATCH), dim3(256), 0, stream>>>(
            sp, bz, lengths, out + BATCH * HDIM, wbuf);
        pv_partial<<<dim3(32, 2, BATCH), dim3(128), 0, stream>>>(wbuf, value, lengths, p2);
        pv_reduce<<<dim3(BATCH), dim3(256), 0, stream>>>(p2, out, 32);
    } else {
        float* sp   = (float*)d_ws;
        float* wbuf = sp + ROWS * NPART;
        float* p2   = wbuf + ROWS;
        score_gemm_fused<<<dim3(4096), dim3(256), 0, stream>>>(
            query, key_, Wq, Wk, bq, bk, Wz, lengths, sp);
        softmax_kernel<<<dim3(BATCH), dim3(256), 0, stream>>>(
            sp, bz, lengths, out + BATCH * HDIM, wbuf);
        pv_partial<<<dim3(16, 2, BATCH), dim3(128), 0, stream>>>(wbuf, value, lengths, p2);
        pv_reduce<<<dim3(BATCH), dim3(256), 0, stream>>>(p2, out, 16);
    }
}

// Round 17
// 314.826 us; speedup vs baseline: 1.0371x; 1.0371x over previous
//
#include <hip/hip_runtime.h>
#include <hip/hip_bf16.h>

constexpr int TSEQ  = 2048;
constexpr int HDIM  = 1024;
constexpr int BATCH = 32;
constexpr int NPART = 16;
constexpr long ROWS = (long)BATCH * TSEQ;  // 65536

// GEMM geometry: 256(M) x 128(N) block, 8 waves (4M x 2N), 64x64 wave tile
constexpr int GBM = 256, GBN = 128;

// fallback (R1) geometry
constexpr int BM = 128, BN = 128, BK = 64;
constexpr int NT = (2 * HDIM) / BK;

typedef __attribute__((ext_vector_type(8))) short bf16x8;
typedef __attribute__((ext_vector_type(8))) unsigned short u16x8;
typedef __attribute__((ext_vector_type(4))) float f32x4;

__device__ __forceinline__ unsigned short f2bf(float f) {
    union { float f; unsigned int u; } v; v.f = f;
    unsigned int r = v.u + 0x7FFFu + ((v.u >> 16) & 1u);  // RTNE
    return (unsigned short)(r >> 16);
}

__device__ __forceinline__ void gload16(const unsigned short* g, unsigned short* l) {
    __builtin_amdgcn_global_load_lds(
        (__attribute__((address_space(1))) void*)(g),
        (__attribute__((address_space(3))) void*)(l), 16, 0, 0);
}

__device__ __forceinline__ float fast_tanh(float x) {
    float e = __expf(2.0f * x);
    return 1.0f - 2.0f * __builtin_amdgcn_rcpf(e + 1.0f);
}

// ---------------- f32 -> bf16 pre-convert (skips masked q/k rows) ----------------
__global__ void convert_kernel(const float* __restrict__ q, const float* __restrict__ k,
                               const float* __restrict__ wq, const float* __restrict__ wk,
                               const int* __restrict__ lengths,
                               unsigned short* __restrict__ qb, unsigned short* __restrict__ kb,
                               unsigned short* __restrict__ wqb, unsigned short* __restrict__ wkb) {
    const long GQ = (ROWS * HDIM) / 8;        // groups of 8 elems
    const long GW = ((long)HDIM * HDIM) / 8;
    const long TOTAL = 2 * GQ + 2 * GW;
    const long stride = (long)gridDim.x * blockDim.x;
    for (long i = (long)blockIdx.x * blockDim.x + threadIdx.x; i < TOTAL; i += stride) {
        const float* src; unsigned short* dst; long off;
        if (i < 2 * GQ) {
            off = (i < GQ) ? i : i - GQ;
            const int row = (int)(off >> 7);                    // HDIM/8 = 128 groups/row
            if ((row & (TSEQ - 1)) >= lengths[row >> 11]) continue;  // masked row: skip
            src = (i < GQ) ? q : k;  dst = (i < GQ) ? qb : kb;
        } else if (i < 2 * GQ + GW) { src = wq; dst = wqb; off = i - 2 * GQ; }
        else                        { src = wk; dst = wkb; off = i - 2 * GQ - GW; }
        float4 v0 = *(const float4*)(src + off * 8);
        float4 v1 = *(const float4*)(src + off * 8 + 4);
        u16x8 o;
        o[0] = f2bf(v0.x); o[1] = f2bf(v0.y); o[2] = f2bf(v0.z); o[3] = f2bf(v0.w);
        o[4] = f2bf(v1.x); o[5] = f2bf(v1.y); o[6] = f2bf(v1.z); o[7] = f2bf(v1.w);
        *(u16x8*)(dst + off * 8) = o;
    }
}

// ------- 256x128 bf16 GEMM: 64x64 wave tile, ring-3 LDS (72 KiB), 2 blocks/CU,  -------
// ------- INTRA-PHASE counted-lgkm MFMA groups (1+3+5+7) for LDS/MFMA overlap.   -------
// Reads pinned in order a0,b0,a1,b1,a2,b2,a3,b3 (DS completes in-order); MFMA group g
// waits only for the frags it needs -> first MFMA after 2 reads land, rest overlap.
__global__ __launch_bounds__(512, 4)
void score_gemm_256(const unsigned short* __restrict__ qb, const unsigned short* __restrict__ kb,
                    const unsigned short* __restrict__ wqb, const unsigned short* __restrict__ wkb,
                    const float* __restrict__ bq, const float* __restrict__ bk,
                    const float* __restrict__ Wz, const int* __restrict__ lengths,
                    float* __restrict__ scorePartial) {
    __shared__ unsigned short As[3 * 256 * 32];  // 48 KiB: ring-3 of A k-halves
    __shared__ unsigned short Bs[3 * 128 * 32];  // 24 KiB: ring-3 of B k-halves

    const int tid  = threadIdx.x;
    const int lane = tid & 63;
    const int wid  = tid >> 6;    // 0..7
    const int wr   = wid >> 1;    // WARPS_M = 4
    const int wc   = wid & 1;     // WARPS_N = 2

    // locality-preserving balanced remap (validated R13): XCD x gets one intra-batch
    // M-slot per batch (rotated); all 8 nb-siblings of an A-panel dispatch-adjacent.
    const int x   = (int)blockIdx.x & 7;
    const int j   = (int)blockIdx.x >> 3;      // 0..255
    const int bat = j >> 3;                    // batch 0..31
    const int nb  = j & 7;                     // 8 N-blocks
    const int mb  = bat * 8 + ((x + bat) & 7); // rotated intra-batch M index
    const long rowBase = (long)mb * GBM;
    const int  colBase = nb * GBN;

    if (((mb & 7) * GBM) >= lengths[bat]) return;   // fully-masked M-block

    const int frow = lane & 15;
    const int cs16 = (((lane >> 4) ^ ((frow >> 1) & 3)) << 4);   // read chunk (XOR-swz)
    const int sc8  = ((tid & 3) ^ ((tid >> 3) & 3)) * 8;         // pre-swizzled source chunk
    const int rowA = wr * 64 + frow;
    const int rowB = wc * 64 + frow;

    f32x4 acc[4][4];
#pragma unroll
    for (int i = 0; i < 4; ++i)
#pragma unroll
        for (int j2 = 0; j2 < 4; ++j2) acc[i][j2] = (f32x4){0.f, 0.f, 0.f, 0.f};

    // stage k-half n into ring slot s: A 16KB (2 rounds) + B 8KB (1 round)
    auto stage = [&](int n, int s) {
        const int tn = n >> 1;
        const unsigned short* asrc = (tn < 16) ? qb : kb;
        const unsigned short* bsrc = (tn < 16) ? wqb : wkb;
        const int ksrc = (tn & 15) * 64 + (n & 1) * 32 + sc8;
        unsigned short* ldsA = As + s * 8192;
        unsigned short* ldsB = Bs + s * 4096;
#pragma unroll
        for (int jj = 0; jj < 2; ++jj)
            gload16(asrc + (rowBase + jj * 128 + (tid >> 2)) * (long)HDIM + ksrc,
                    ldsA + jj * 4096 + (tid << 3));
        gload16(bsrc + (long)(colBase + (tid >> 2)) * HDIM + ksrc, ldsB + (tid << 3));
    };

    // prologue: stage halves 0,1; drain half 0 (vmcnt(3) keeps stage(1) in flight)
    stage(0, 0);
    stage(1, 1);
    asm volatile("s_waitcnt vmcnt(3)" ::: "memory");
    __builtin_amdgcn_s_barrier();

    int cur = 0;
    for (int n = 0; n < 64; ++n) {
        const char* pA = (const char*)As + cur * 16384;
        const char* pB = (const char*)Bs + cur * 8192;
        bf16x8 afr[4], bfr[4];
        // pinned-order interleaved reads: a0,b0 | a1,b1 | a2,b2 | a3,b3
        afr[0] = *(const bf16x8*)(pA + (rowA + 0 * 16) * 64 + cs16);
        bfr[0] = *(const bf16x8*)(pB + (rowB + 0 * 16) * 64 + cs16);
        __builtin_amdgcn_sched_barrier(0);
        afr[1] = *(const bf16x8*)(pA + (rowA + 1 * 16) * 64 + cs16);
        bfr[1] = *(const bf16x8*)(pB + (rowB + 1 * 16) * 64 + cs16);
        __builtin_amdgcn_sched_barrier(0);
        afr[2] = *(const bf16x8*)(pA + (rowA + 2 * 16) * 64 + cs16);
        bfr[2] = *(const bf16x8*)(pB + (rowB + 2 * 16) * 64 + cs16);
        __builtin_amdgcn_sched_barrier(0);
        afr[3] = *(const bf16x8*)(pA + (rowA + 3 * 16) * 64 + cs16);
        bfr[3] = *(const bf16x8*)(pB + (rowB + 3 * 16) * 64 + cs16);
        __builtin_amdgcn_sched_barrier(0);
        if (n <= 61) stage(n + 2, (cur >= 1) ? cur - 1 : cur + 2);   // slot (n+2)%3

#define MM(mi, ni) acc[mi][ni] = __builtin_amdgcn_mfma_f32_16x16x32_bf16( \
        afr[mi], bfr[ni], acc[mi][ni], 0, 0, 0)
        __builtin_amdgcn_s_setprio(1);
        asm volatile("s_waitcnt lgkmcnt(6)" ::: "memory");   // a0,b0 landed
        __builtin_amdgcn_sched_barrier(0);
        MM(0, 0);
        asm volatile("s_waitcnt lgkmcnt(4)" ::: "memory");   // +a1,b1
        __builtin_amdgcn_sched_barrier(0);
        MM(0, 1); MM(1, 0); MM(1, 1);
        asm volatile("s_waitcnt lgkmcnt(2)" ::: "memory");   // +a2,b2
        __builtin_amdgcn_sched_barrier(0);
        MM(0, 2); MM(1, 2); MM(2, 0); MM(2, 1); MM(2, 2);
        asm volatile("s_waitcnt lgkmcnt(0)" ::: "memory");   // +a3,b3
        __builtin_amdgcn_sched_barrier(0);
        MM(0, 3); MM(1, 3); MM(2, 3); MM(3, 0); MM(3, 1); MM(3, 2); MM(3, 3);
        __builtin_amdgcn_s_setprio(0);
#undef MM
        // drain stage(n+1) for next phase; keep stage(n+2) in flight
        if (n <= 61)      asm volatile("s_waitcnt vmcnt(3)" ::: "memory");
        else if (n == 62) asm volatile("s_waitcnt vmcnt(0)" ::: "memory");
        if (n < 63) __builtin_amdgcn_s_barrier();
        cur = (cur == 2) ? 0 : cur + 1;
    }

    // epilogue: p[row] = sum_cols tanh(s + bq + bk) * Wz
    float bias[4], wz[4];
#pragma unroll
    for (int ni = 0; ni < 4; ++ni) {
        const int o = colBase + wc * 64 + ni * 16 + frow;
        bias[ni] = bq[o] + bk[o];
        wz[ni]   = Wz[o];
    }
#pragma unroll
    for (int mi = 0; mi < 4; ++mi) {
#pragma unroll
        for (int jj = 0; jj < 4; ++jj) {
            float p = 0.f;
#pragma unroll
            for (int ni = 0; ni < 4; ++ni)
                p += fast_tanh(acc[mi][ni][jj] + bias[ni]) * wz[ni];
#pragma unroll
            for (int off = 1; off < 16; off <<= 1) p += __shfl_xor(p, off);
            if (frow == 0) {
                long r = rowBase + wr * 64 + mi * 16 + (lane >> 4) * 4 + jj;
                scorePartial[r * NPART + nb * 2 + wc] = p;
            }
        }
    }
}

// ---------------- fallback: round-1 fused f32 GEMM (with early-out) ----------------
__global__ __launch_bounds__(256, 2)
void score_gemm_fused(const float* __restrict__ query, const float* __restrict__ key_,
                      const float* __restrict__ Wq, const float* __restrict__ Wk,
                      const float* __restrict__ bq, const float* __restrict__ bk,
                      const float* __restrict__ Wz, const int* __restrict__ lengths,
                      float* __restrict__ scorePartial) {
    __shared__ unsigned short As[2][BM * BK];
    __shared__ unsigned short Bs[2][BN * BK];
    const int tid  = threadIdx.x;
    const int lane = tid & 63;
    const int wid  = tid >> 6;
    const int wr   = wid >> 1, wc = wid & 1;
    const int bid = blockIdx.x;
    const int nb  = bid & 7;
    const int mb  = bid >> 3;
    const long rowBase = (long)mb * BM;
    const int  colBase = nb * BN;
    if ((int)(rowBase & (TSEQ - 1)) >= lengths[(int)(rowBase >> 11)]) return;
    const int srow = tid >> 4;
    const int sc   = tid & 15;
    const int rA  = wr * 64 + (lane & 15);
    const int rB  = wc * 64 + (lane & 15);
    const int swz = (lane & 7) << 4;
    const int kb  = (lane >> 4) << 4;

    f32x4 acc[4][4];
#pragma unroll
    for (int i = 0; i < 4; i++)
#pragma unroll
        for (int j = 0; j < 4; j++) acc[i][j] = (f32x4){0.f, 0.f, 0.f, 0.f};

    float4 regA[8], regB[8];
    auto stage_load = [&](int kt) {
        const int kg = kt * BK;
        const float* baseA; const float* baseB; int koff;
        if (kg < HDIM) { baseA = query; baseB = Wq; koff = kg; }
        else           { baseA = key_;  baseB = Wk; koff = kg - HDIM; }
#pragma unroll
        for (int i = 0; i < 8; i++) {
            int row = i * 16 + srow;
            regA[i] = *(const float4*)(baseA + (rowBase + row) * (long)HDIM + koff + sc * 4);
            regB[i] = *(const float4*)(baseB + (long)(colBase + row) * HDIM + koff + sc * 4);
        }
    };
    auto stage_write = [&](int buf) {
#pragma unroll
        for (int i = 0; i < 8; i++) {
            int row = i * 16 + srow;
            int off = row * 128 + (((sc * 8)) ^ ((row & 7) << 4));
            ushort4 ha, hb;
            ha.x = f2bf(regA[i].x); ha.y = f2bf(regA[i].y);
            ha.z = f2bf(regA[i].z); ha.w = f2bf(regA[i].w);
            hb.x = f2bf(regB[i].x); hb.y = f2bf(regB[i].y);
            hb.z = f2bf(regB[i].z); hb.w = f2bf(regB[i].w);
            *(ushort4*)((char*)&As[buf][0] + off) = ha;
            *(ushort4*)((char*)&Bs[buf][0] + off) = hb;
        }
    };
    auto compute = [&](int buf) {
        const char* pA = (const char*)&As[buf][0];
        const char* pB = (const char*)&Bs[buf][0];
        bf16x8 a[4][2], b[4][2];
#pragma unroll
        for (int h = 0; h < 2; h++) {
#pragma unroll
            for (int mi = 0; mi < 4; mi++)
                a[mi][h] = *(const bf16x8*)(pA + (((rA + mi * 16) * 128 + h * 64 + kb) ^ swz));
#pragma unroll
            for (int ni = 0; ni < 4; ni++)
                b[ni][h] = *(const bf16x8*)(pB + (((rB + ni * 16) * 128 + h * 64 + kb) ^ swz));
        }
#pragma unroll
        for (int h = 0; h < 2; h++)
#pragma unroll
            for (int mi = 0; mi < 4; mi++)
#pragma unroll
                for (int ni = 0; ni < 4; ni++)
                    acc[mi][ni] = __builtin_amdgcn_mfma_f32_16x16x32_bf16(
                        a[mi][h], b[ni][h], acc[mi][ni], 0, 0, 0);
    };

    stage_load(0);
    stage_write(0);
    __syncthreads();
    int buf = 0;
    for (int kt = 1; kt < NT; ++kt) {
        stage_load(kt);
        compute(buf);
        stage_write(buf ^ 1);
        __syncthreads();
        buf ^= 1;
    }
    compute(buf);

    float bias[4], wz[4];
#pragma unroll
    for (int ni = 0; ni < 4; ni++) {
        int o = colBase + wc * 64 + ni * 16 + (lane & 15);
        bias[ni] = bq[o] + bk[o];
        wz[ni]   = Wz[o];
    }
#pragma unroll
    for (int mi = 0; mi < 4; mi++) {
#pragma unroll
        for (int j = 0; j < 4; j++) {
            float p = 0.f;
#pragma unroll
            for (int ni = 0; ni < 4; ni++) {
                float s = acc[mi][ni][j] + bias[ni];
                p += fast_tanh(s) * wz[ni];
            }
#pragma unroll
            for (int off = 1; off < 16; off <<= 1) p += __shfl_xor(p, off);
            if ((lane & 15) == 0) {
                long r = rowBase + wr * 64 + mi * 16 + (lane >> 4) * 4 + j;
                scorePartial[r * NPART + nb * 2 + wc] = p;
            }
        }
    }
}

// ---------------- shared tail kernels ----------------
__global__ void softmax_kernel(const float* __restrict__ sp, const float* __restrict__ bzp,
                               const int* __restrict__ lengths,
                               float* __restrict__ w_out, float* __restrict__ w_ws) {
    const int b = blockIdx.x;
    const int tid = threadIdx.x;  // 256
    const int len = lengths[b];
    const float bz = bzp[0];
    float sv[8];
    float m = -3.0e38f;
#pragma unroll
    for (int i = 0; i < 8; i++) {
        int t = i * 256 + tid;
        const float4* p = (const float4*)(sp + ((long)b * TSEQ + t) * NPART);
        float s;
        if (t >= len) {
            s = -1e9f;   // masked: never read sp (may be unwritten garbage)
        } else {
            float4 a = p[0], c = p[1], d = p[2], e = p[3];
            s = (a.x + a.y + a.z + a.w) + (c.x + c.y + c.z + c.w) +
                (d.x + d.y + d.z + d.w) + (e.x + e.y + e.z + e.w) + bz;
        }
        sv[i] = s;
        m = fmaxf(m, s);
    }
    __shared__ float redm[4];
    __shared__ float reds[4];
    for (int off = 32; off; off >>= 1) m = fmaxf(m, __shfl_xor(m, off));
    if ((tid & 63) == 0) redm[tid >> 6] = m;
    __syncthreads();
    m = fmaxf(fmaxf(redm[0], redm[1]), fmaxf(redm[2], redm[3]));
    float sum = 0.f;
    float ev[8];
#pragma unroll
    for (int i = 0; i < 8; i++) {
        ev[i] = expf(sv[i] - m);
        sum += ev[i];
    }
    for (int off = 32; off; off >>= 1) sum += __shfl_xor(sum, off);
    if ((tid & 63) == 0) reds[tid >> 6] = sum;
    __syncthreads();
    sum = reds[0] + reds[1] + reds[2] + reds[3];
    const float inv = 1.0f / sum;
#pragma unroll
    for (int i = 0; i < 8; i++) {
        int t = i * 256 + tid;
        float w = ev[i] * inv;
        w_out[(long)b * TSEQ + t] = w;
        w_ws[(long)b * TSEQ + t] = w;
    }
}

__global__ void pv_partial(const float* __restrict__ w, const float* __restrict__ value,
                           const int* __restrict__ lengths, float* __restrict__ part) {
    const int ntc = gridDim.x;
    const int tchunk = TSEQ / ntc;
    const int tc = blockIdx.x;
    const int hc = blockIdx.y;
    const int b  = blockIdx.z;
    const int tid = threadIdx.x; // 128
    const int h = hc * 512 + tid * 4;
    float* dst = part + ((long)(b * ntc + tc)) * HDIM + h;
    if (tc * tchunk >= lengths[b]) {    // fully-masked chunk: zero partial, skip loads
        *(float4*)dst = (float4){0.f, 0.f, 0.f, 0.f};
        return;
    }
    __shared__ float sw[128];
    if (tid < tchunk) sw[tid] = w[(long)b * TSEQ + tc * tchunk + tid];
    __syncthreads();
    float4 acc = {0.f, 0.f, 0.f, 0.f};
    const float* vbase = value + ((long)b * TSEQ + tc * tchunk) * HDIM + h;
#pragma unroll 4
    for (int tt = 0; tt < tchunk; ++tt) {
        float4 v = *(const float4*)(vbase + (long)tt * HDIM);
        float wv = sw[tt];
        acc.x += wv * v.x; acc.y += wv * v.y;
        acc.z += wv * v.z; acc.w += wv * v.w;
    }
    *(float4*)dst = acc;
}

__global__ void pv_reduce(const float* __restrict__ part, float* __restrict__ out, int ntc) {
    const int b = blockIdx.x;    // 32
    const int tid = threadIdx.x; // 256
    const int h = tid * 4;
    float4 acc = {0.f, 0.f, 0.f, 0.f};
    for (int tc = 0; tc < ntc; ++tc) {
        float4 v = *(const float4*)(part + ((long)(b * ntc + tc)) * HDIM + h);
        acc.x += v.x; acc.y += v.y; acc.z += v.z; acc.w += v.w;
    }
    *(float4*)(out + (long)b * HDIM + h) = acc;
}

extern "C" void kernel_launch(void* const* d_in, const int* in_sizes, int n_in,
                              void* d_out, int out_size, void* d_ws, size_t ws_size,
                              hipStream_t stream) {
    const float* query   = (const float*)d_in[0];
    const float* key_    = (const float*)d_in[1];
    const float* value   = (const float*)d_in[2];
    const int*   lengths = (const int*)d_in[3];
    const float* Wq = (const float*)d_in[4];
    const float* bq = (const float*)d_in[5];
    const float* Wk = (const float*)d_in[6];
    const float* bk = (const float*)d_in[7];
    const float* Wz = (const float*)d_in[8];
    const float* bz = (const float*)d_in[9];
    float* out = (float*)d_out;

    const long QB_B  = ROWS * HDIM * 2;
    const long WB_B  = (long)HDIM * HDIM * 2;
    const long SP_B  = ROWS * NPART * 4;
    const long WW_B  = ROWS * 4;
    const long P2_B  = (long)BATCH * 32 * HDIM * 4;
    const long NEED  = 2 * QB_B + 2 * WB_B + SP_B + WW_B + P2_B;

    if ((long)ws_size >= NEED) {
        char* w = (char*)d_ws;
        unsigned short* qb  = (unsigned short*)w;            w += QB_B;
        unsigned short* kb  = (unsigned short*)w;            w += QB_B;
        unsigned short* wqb = (unsigned short*)w;            w += WB_B;
        unsigned short* wkb = (unsigned short*)w;            w += WB_B;
        float* sp   = (float*)w;                             w += SP_B;
        float* wbuf = (float*)w;                             w += WW_B;
        float* p2   = (float*)w;

        convert_kernel<<<dim3(4096), dim3(256), 0, stream>>>(
            query, key_, Wq, Wk, lengths, qb, kb, wqb, wkb);
        // grid = 256 M-blocks x 8 N-blocks = 2048
        score_gemm_256<<<dim3(2048), dim3(512), 0, stream>>>(
            qb, kb, wqb, wkb, bq, bk, Wz, lengths, sp);
        softmax_kernel<<<dim3(BATCH), dim3(256), 0, stream>>>(
            sp, bz, lengths, out + BATCH * HDIM, wbuf);
        pv_partial<<<dim3(32, 2, BATCH), dim3(128), 0, stream>>>(wbuf, value, lengths, p2);
        pv_reduce<<<dim3(BATCH), dim3(256), 0, stream>>>(p2, out, 32);
    } else {
        float* sp   = (float*)d_ws;
        float* wbuf = sp + ROWS * NPART;
        float* p2   = wbuf + ROWS;
        score_gemm_fused<<<dim3(4096), dim3(256), 0, stream>>>(
            query, key_, Wq, Wk, bq, bk, Wz, lengths, sp);
        softmax_kernel<<<dim3(BATCH), dim3(256), 0, stream>>>(
            sp, bz, lengths, out + BATCH * HDIM, wbuf);
        pv_partial<<<dim3(16, 2, BATCH), dim3(128), 0, stream>>>(wbuf, value, lengths, p2);
        pv_reduce<<<dim3(BATCH), dim3(256), 0, stream>>>(p2, out, 16);
    }
}